// Round 1
// baseline (3341.461 us; speedup 1.0000x reference)
//
#include <hip/hip_runtime.h>
#include <math.h>

#define NN 50
#define E2 400
#define ET 450
#define NTHR 256

// Fiedler/ev0 sign choice: canonicalize so max-|entry| component is positive,
// then multiply by these (empirical knobs for matching LAPACK's arbitrary sign).
#define SIGN0 (1.0f)
#define SIGN1 (1.0f)

__global__ __launch_bounds__(NTHR) void opn_kernel(
    const float* __restrict__ gx, const int* __restrict__ gedge,
    const float* __restrict__ gmask,
    const float* __restrict__ w1, const float* __restrict__ as1,
    const float* __restrict__ ad1, const float* __restrict__ b1,
    const float* __restrict__ w2, const float* __restrict__ as2,
    const float* __restrict__ ad2, const float* __restrict__ b2,
    const float* __restrict__ miw, const float* __restrict__ mib,
    const float* __restrict__ mow, const float* __restrict__ mob,
    const float* __restrict__ wq, const float* __restrict__ bq,
    const float* __restrict__ wk, const float* __restrict__ bk,
    const float* __restrict__ wv, const float* __restrict__ bv,
    const float* __restrict__ ws, const float* __restrict__ bs,
    const float* __restrict__ mw1, const float* __restrict__ mb1,
    const float* __restrict__ mw2, const float* __restrict__ mb2,
    const float* __restrict__ cw, const float* __restrict__ cb,
    float* __restrict__ out)
{
    const int tid = threadIdx.x;

    __shared__ float sM[NN * NN];   // A -> L -> Jacobi M -> attn -> logits
    __shared__ float sS[3200];      // Jacobi ping buffer -> GAT1 h8/o8 -> MLP hid64
    __shared__ float sV[NN * NN];   // eigenvectors
    __shared__ float sX[NN * 5];    // x_combined (kept until output)
    __shared__ float sH5a[NN * 5];
    __shared__ float sH5b[NN * 5];
    __shared__ float sH5c[NN * 5];
    __shared__ float sH5d[NN * 5];
    __shared__ int   sSrc[ET];
    __shared__ int   sDst[ET];
    __shared__ float sE[ET];
    __shared__ float sAl[ET];
    __shared__ float sNm[NN];
    __shared__ float sNs[NN];
    __shared__ float sAs[NN];
    __shared__ float sAd[NN];
    __shared__ float sc_[25];
    __shared__ float ss_[25];
    __shared__ int   sp_[25];
    __shared__ int   sq_[25];
    __shared__ int   rPair[NN];
    __shared__ int   rRole[NN];
    __shared__ float sdis[NN];
    __shared__ float sred[NTHR];
    __shared__ int   ssel[2];
    __shared__ float ssgn[2];

    // ---------------- edges (with self loops) + adjacency ----------------
    for (int t = tid; t < ET; t += NTHR) {
        int s, d;
        if (t < E2) { s = gedge[t]; d = gedge[E2 + t]; }
        else        { s = t - E2;   d = t - E2; }
        sSrc[t] = s; sDst[t] = d;
    }
    for (int t = tid; t < NN * NN; t += NTHR) sM[t] = 0.0f;
    __syncthreads();
    for (int t = tid; t < E2; t += NTHR)
        atomicAdd(&sM[sSrc[t] * NN + sDst[t]], 1.0f);
    __syncthreads();

    // ---------------- sym-normalized Laplacian ----------------
    for (int i = tid; i < NN; i += NTHR) {
        float dsum = 0.0f;
        for (int j = 0; j < NN; ++j) dsum += sM[i * NN + j];
        sdis[i] = (dsum > 0.0f) ? (1.0f / sqrtf(fmaxf(dsum, 1e-12f))) : 0.0f;
    }
    __syncthreads();
    for (int t = tid; t < NN * NN; t += NTHR) {
        int i = t / NN, j = t % NN;
        sM[t] = ((i == j) ? 1.0f : 0.0f) - sdis[i] * sM[t] * sdis[j];
    }
    for (int t = tid; t < NN * NN; t += NTHR)
        sV[t] = (t / NN == t % NN) ? 1.0f : 0.0f;
    __syncthreads();

    // ---------------- parallel round-robin Jacobi eigensolver ----------------
    for (int sweep = 0; sweep < 16; ++sweep) {
        for (int r = 0; r < NN - 1; ++r) {
            if (tid < 25) {
                int j = tid;
                int p = (j == 0) ? 0 : ((j - 1 + r) % (NN - 1)) + 1;
                int q = ((NN - 2 - j + r) % (NN - 1)) + 1;
                float app = sM[p * NN + p];
                float aqq = sM[q * NN + q];
                float apq = sM[p * NN + q];
                float c, s;
                if (fabsf(apq) > 1e-12f) {
                    float tau = (aqq - app) / (2.0f * apq);
                    float tt = ((tau >= 0.0f) ? 1.0f : -1.0f) /
                               (fabsf(tau) + sqrtf(1.0f + tau * tau));
                    c = 1.0f / sqrtf(1.0f + tt * tt);
                    s = tt * c;
                } else { c = 1.0f; s = 0.0f; }
                sc_[j] = c; ss_[j] = s; sp_[j] = p; sq_[j] = q;
                rPair[p] = j; rRole[p] = 0;
                rPair[q] = j; rRole[q] = 1;
            }
            __syncthreads();
            // row phase: sM -> sS
            for (int t = tid; t < NN * NN; t += NTHR) {
                int i = t / NN, k = t % NN;
                int j = rPair[i];
                float c = sc_[j], s = ss_[j];
                float vp = sM[sp_[j] * NN + k];
                float vq = sM[sq_[j] * NN + k];
                sS[t] = (rRole[i] == 0) ? (c * vp - s * vq) : (s * vp + c * vq);
            }
            __syncthreads();
            // col phase: sS -> sM; V updated pairwise (race-free)
            for (int t = tid; t < NN * NN; t += NTHR) {
                int k = t / NN, i = t % NN;
                int j = rPair[i];
                float c = sc_[j], s = ss_[j];
                float vp = sS[k * NN + sp_[j]];
                float vq = sS[k * NN + sq_[j]];
                sM[t] = (rRole[i] == 0) ? (c * vp - s * vq) : (s * vp + c * vq);
            }
            for (int t = tid; t < NN * 25; t += NTHR) {
                int k = t / 25, j = t % 25;
                float c = sc_[j], s = ss_[j];
                int p = sp_[j], q = sq_[j];
                float vp = sV[k * NN + p], vq = sV[k * NN + q];
                sV[k * NN + p] = c * vp - s * vq;
                sV[k * NN + q] = s * vp + c * vq;
            }
            __syncthreads();
        }
    }

    // ---------------- pick two smallest eigenvalues, canonicalize signs ----------------
    if (tid == 0) {
        int i0 = -1, i1 = -1;
        float e0 = 1e30f, e1 = 1e30f;
        for (int i = 0; i < NN; ++i) {
            float d = sM[i * NN + i];
            if (d < e0)      { e1 = e0; i1 = i0; e0 = d; i0 = i; }
            else if (d < e1) { e1 = d; i1 = i; }
        }
        ssel[0] = i0; ssel[1] = i1;
        for (int cidx = 0; cidx < 2; ++cidx) {
            int col = ssel[cidx];
            float best = -1.0f, bv = 0.0f;
            for (int i = 0; i < NN; ++i) {
                float v = sV[i * NN + col];
                if (fabsf(v) > best) { best = fabsf(v); bv = v; }
            }
            ssgn[cidx] = (bv >= 0.0f) ? 1.0f : -1.0f;
        }
        ssgn[0] *= SIGN0; ssgn[1] *= SIGN1;
    }
    __syncthreads();
    for (int i = tid; i < NN; i += NTHR) {
        sX[i * 5 + 0] = gx[i * 3 + 0];
        sX[i * 5 + 1] = gx[i * 3 + 1];
        sX[i * 5 + 2] = gx[i * 3 + 2];
        sX[i * 5 + 3] = ssgn[0] * sV[i * NN + ssel[0]];
        sX[i * 5 + 4] = ssgn[1] * sV[i * NN + ssel[1]];
    }
    __syncthreads();

    // ---------------- GAT layer 1 (5 -> 8) + ReLU ----------------
    float* h8 = sS;          // 50x8
    float* o8 = sS + 1600;   // 50x8
    for (int t = tid; t < NN * 8; t += NTHR) {
        int i = t / 8, o = t % 8;
        float acc = 0.0f;
        for (int k = 0; k < 5; ++k) acc += sX[i * 5 + k] * w1[o * 5 + k];
        h8[t] = acc;
    }
    __syncthreads();
    for (int i = tid; i < NN; i += NTHR) {
        float a = 0.0f, b = 0.0f;
        for (int o = 0; o < 8; ++o) {
            a += h8[i * 8 + o] * as1[o];
            b += h8[i * 8 + o] * ad1[o];
        }
        sAs[i] = a; sAd[i] = b;
    }
    __syncthreads();
    for (int e = tid; e < ET; e += NTHR) {
        float v = sAs[sSrc[e]] + sAd[sDst[e]];
        sE[e] = (v > 0.0f) ? v : 0.2f * v;
    }
    __syncthreads();
    for (int i = tid; i < NN; i += NTHR) {
        float m = -1e30f;
        for (int e = 0; e < ET; ++e) if (sDst[e] == i) m = fmaxf(m, sE[e]);
        float su = 0.0f;
        for (int e = 0; e < ET; ++e) if (sDst[e] == i) su += expf(sE[e] - m);
        sNm[i] = m; sNs[i] = su;
    }
    __syncthreads();
    for (int e = tid; e < ET; e += NTHR)
        sAl[e] = expf(sE[e] - sNm[sDst[e]]) / (sNs[sDst[e]] + 1e-16f);
    __syncthreads();
    for (int t = tid; t < NN * 8; t += NTHR) {
        int i = t / 8, o = t % 8;
        float acc = b1[o];
        for (int e = 0; e < ET; ++e)
            if (sDst[e] == i) acc += sAl[e] * h8[sSrc[e] * 8 + o];
        o8[t] = fmaxf(acc, 0.0f);
    }
    __syncthreads();

    // ---------------- GAT layer 2 (8 -> 5) ----------------
    for (int t = tid; t < NN * 5; t += NTHR) {
        int i = t / 5, o = t % 5;
        float acc = 0.0f;
        for (int k = 0; k < 8; ++k) acc += o8[i * 8 + k] * w2[o * 8 + k];
        sH5a[t] = acc;
    }
    __syncthreads();
    for (int i = tid; i < NN; i += NTHR) {
        float a = 0.0f, b = 0.0f;
        for (int o = 0; o < 5; ++o) {
            a += sH5a[i * 5 + o] * as2[o];
            b += sH5a[i * 5 + o] * ad2[o];
        }
        sAs[i] = a; sAd[i] = b;
    }
    __syncthreads();
    for (int e = tid; e < ET; e += NTHR) {
        float v = sAs[sSrc[e]] + sAd[sDst[e]];
        sE[e] = (v > 0.0f) ? v : 0.2f * v;
    }
    __syncthreads();
    for (int i = tid; i < NN; i += NTHR) {
        float m = -1e30f;
        for (int e = 0; e < ET; ++e) if (sDst[e] == i) m = fmaxf(m, sE[e]);
        float su = 0.0f;
        for (int e = 0; e < ET; ++e) if (sDst[e] == i) su += expf(sE[e] - m);
        sNm[i] = m; sNs[i] = su;
    }
    __syncthreads();
    for (int e = tid; e < ET; e += NTHR)
        sAl[e] = expf(sE[e] - sNm[sDst[e]]) / (sNs[sDst[e]] + 1e-16f);
    __syncthreads();
    for (int t = tid; t < NN * 5; t += NTHR) {
        int i = t / 5, o = t % 5;
        float acc = b2[o];
        for (int e = 0; e < ET; ++e)
            if (sDst[e] == i) acc += sAl[e] * sH5a[sSrc[e] * 5 + o];
        sH5b[t] = acc;
    }
    __syncthreads();

    // ---------------- MultiheadAttention (1 head, seq=N) ----------------
    for (int t = tid; t < NN * 15; t += NTHR) {
        int i = t / 15, o = t % 15;
        float acc = mib[o];
        for (int k = 0; k < 5; ++k) acc += sH5b[i * 5 + k] * miw[o * 5 + k];
        if (o < 5)       sH5c[i * 5 + o] = acc;        // q
        else if (o < 10) sH5d[i * 5 + (o - 5)] = acc;  // k
        else             sH5a[i * 5 + (o - 10)] = acc; // v
    }
    __syncthreads();
    const float inv_sqrt5 = 0.4472135954999579f;
    for (int t = tid; t < NN * NN; t += NTHR) {
        int i = t / NN, j = t % NN;
        float acc = 0.0f;
        for (int k = 0; k < 5; ++k) acc += sH5c[i * 5 + k] * sH5d[j * 5 + k];
        sM[t] = acc * inv_sqrt5;
    }
    __syncthreads();
    for (int i = tid; i < NN; i += NTHR) {
        float m = -1e30f;
        for (int j = 0; j < NN; ++j) m = fmaxf(m, sM[i * NN + j]);
        float su = 0.0f;
        for (int j = 0; j < NN; ++j) su += expf(sM[i * NN + j] - m);
        float inv = 1.0f / su;
        for (int j = 0; j < NN; ++j)
            sM[i * NN + j] = expf(sM[i * NN + j] - m) * inv;
    }
    __syncthreads();
    for (int t = tid; t < NN * 5; t += NTHR) {
        int i = t / 5, f = t % 5;
        float acc = 0.0f;
        for (int j = 0; j < NN; ++j) acc += sM[i * NN + j] * sH5a[j * 5 + f];
        sH5c[t] = acc;  // attn @ v (q buffer is free)
    }
    __syncthreads();
    for (int t = tid; t < NN * 5; t += NTHR) {
        int i = t / 5, o = t % 5;
        float acc = mob[o];
        for (int k = 0; k < 5; ++k) acc += sH5c[i * 5 + k] * mow[o * 5 + k];
        sH5d[t] = acc;  // hM (k buffer is free)
    }
    __syncthreads();

    // ---------------- TransformerConv ----------------
    for (int t = tid; t < NN * 5; t += NTHR) {
        int i = t / 5, o = t % 5;
        float q_ = bq[o], k_ = bk[o], v_ = bv[o];
        for (int k = 0; k < 5; ++k) {
            float h = sH5d[i * 5 + k];
            q_ += h * wq[o * 5 + k];
            k_ += h * wk[o * 5 + k];
            v_ += h * wv[o * 5 + k];
        }
        sH5a[t] = q_; sH5b[t] = k_; sH5c[t] = v_;
    }
    __syncthreads();
    for (int e = tid; e < ET; e += NTHR) {
        float acc = 0.0f;
        int s2 = sSrc[e], d2 = sDst[e];
        for (int k = 0; k < 5; ++k) acc += sH5a[d2 * 5 + k] * sH5b[s2 * 5 + k];
        sE[e] = acc * inv_sqrt5;
    }
    __syncthreads();
    for (int i = tid; i < NN; i += NTHR) {
        float m = -1e30f;
        for (int e = 0; e < ET; ++e) if (sDst[e] == i) m = fmaxf(m, sE[e]);
        float su = 0.0f;
        for (int e = 0; e < ET; ++e) if (sDst[e] == i) su += expf(sE[e] - m);
        sNm[i] = m; sNs[i] = su;
    }
    __syncthreads();
    for (int e = tid; e < ET; e += NTHR)
        sAl[e] = expf(sE[e] - sNm[sDst[e]]) / (sNs[sDst[e]] + 1e-16f);
    __syncthreads();
    for (int t = tid; t < NN * 5; t += NTHR) {
        int i = t / 5, o = t % 5;
        float acc = bs[o];
        for (int k = 0; k < 5; ++k) acc += sH5d[i * 5 + k] * ws[o * 5 + k];
        for (int e = 0; e < ET; ++e)
            if (sDst[e] == i) acc += sAl[e] * sH5c[sSrc[e] * 5 + o];
        sH5a[t] = acc;  // tc output (q buffer is free)
    }
    __syncthreads();

    // ---------------- MLP aggregation head ----------------
    for (int t = tid; t < NN * 64; t += NTHR) {
        int i = t >> 6, o = t & 63;
        float acc = mb1[o];
        for (int k = 0; k < 5; ++k) acc += sH5a[i * 5 + k] * mw1[o * 250 + k];
        sS[t] = fmaxf(acc, 0.0f);
    }
    __syncthreads();
    for (int t = tid; t < NN * NN; t += NTHR) {
        int i = t / NN, j = t % NN;
        float acc = mb2[j];
        for (int k = 0; k < 64; ++k) acc += sS[i * 64 + k] * mw2[j * 64 + k];
        sM[t] = acc;                 // unmasked logits (for value)
        out[t] = acc * gmask[j];     // masked logits output
    }
    __syncthreads();

    // ---------------- value (critic) ----------------
    float part = 0.0f;
    for (int t = tid; t < NN * NN; t += NTHR) part += sM[t] * cw[t % NN];
    sred[tid] = part;
    __syncthreads();
    for (int off = NTHR / 2; off > 0; off >>= 1) {
        if (tid < off) sred[tid] += sred[tid + off];
        __syncthreads();
    }
    if (tid == 0) out[2500] = sred[0] * (1.0f / NN) + cb[0];

    // ---------------- x_combined + ei outputs ----------------
    for (int t = tid; t < NN * 5; t += NTHR) out[2501 + t] = sX[t];
    for (int t = tid; t < 2 * ET; t += NTHR) {
        int row = t / ET, c2 = t % ET;
        int val = (c2 < E2) ? gedge[row * E2 + c2] : (c2 - E2);
        out[2751 + t] = (float)val;
    }
}

extern "C" void kernel_launch(void* const* d_in, const int* in_sizes, int n_in,
                              void* d_out, int out_size, void* d_ws, size_t ws_size,
                              hipStream_t stream) {
    (void)in_sizes; (void)n_in; (void)d_ws; (void)ws_size; (void)out_size;
    opn_kernel<<<1, NTHR, 0, stream>>>(
        (const float*)d_in[0], (const int*)d_in[1], (const float*)d_in[2],
        (const float*)d_in[3], (const float*)d_in[4], (const float*)d_in[5], (const float*)d_in[6],
        (const float*)d_in[7], (const float*)d_in[8], (const float*)d_in[9], (const float*)d_in[10],
        (const float*)d_in[11], (const float*)d_in[12], (const float*)d_in[13], (const float*)d_in[14],
        (const float*)d_in[15], (const float*)d_in[16], (const float*)d_in[17], (const float*)d_in[18],
        (const float*)d_in[19], (const float*)d_in[20], (const float*)d_in[21], (const float*)d_in[22],
        (const float*)d_in[23], (const float*)d_in[24], (const float*)d_in[25], (const float*)d_in[26],
        (const float*)d_in[27], (const float*)d_in[28],
        (float*)d_out);
}

// Round 2
// 483.000 us; speedup vs baseline: 6.9181x; 6.9181x over previous
//
#include <hip/hip_runtime.h>
#include <math.h>

#define NN 50
#define E2 400
#define ET 450
#define NTHR 256
#define SWEEPS 10

#define SIGN0 (1.0f)
#define SIGN1 (1.0f)

__global__ __launch_bounds__(NTHR) void opn_kernel(
    const float* __restrict__ gx, const int* __restrict__ gedge,
    const float* __restrict__ gmask,
    const float* __restrict__ w1, const float* __restrict__ as1,
    const float* __restrict__ ad1, const float* __restrict__ b1,
    const float* __restrict__ w2, const float* __restrict__ as2,
    const float* __restrict__ ad2, const float* __restrict__ b2,
    const float* __restrict__ miw, const float* __restrict__ mib,
    const float* __restrict__ mow, const float* __restrict__ mob,
    const float* __restrict__ wq, const float* __restrict__ bq,
    const float* __restrict__ wk, const float* __restrict__ bk,
    const float* __restrict__ wv, const float* __restrict__ bv,
    const float* __restrict__ ws, const float* __restrict__ bs,
    const float* __restrict__ mw1, const float* __restrict__ mb1,
    const float* __restrict__ mw2, const float* __restrict__ mb2,
    const float* __restrict__ cw, const float* __restrict__ cb,
    float* __restrict__ out)
{
    const int tid = threadIdx.x;

    __shared__ float sM[NN * NN];   // A -> L -> Jacobi M -> attn -> logits
    __shared__ float sS[3200];      // Jacobi ping buffer -> GAT1 h8/o8 -> MLP hid64
    __shared__ float sV[NN * NN];   // eigenvectors
    __shared__ float sX[NN * 5];    // x_combined (kept until output)
    __shared__ float sH5a[NN * 5];
    __shared__ float sH5b[NN * 5];
    __shared__ float sH5c[NN * 5];
    __shared__ float sH5d[NN * 5];
    __shared__ int   sSrc[ET];
    __shared__ int   sDst[ET];
    __shared__ float sE[ET];
    __shared__ float sAl[ET];
    __shared__ float sNm[NN];
    __shared__ float sNs[NN];
    __shared__ float sAs[NN];
    __shared__ float sAd[NN];
    __shared__ float sdis[NN];
    __shared__ float sred[NTHR];
    __shared__ int   ssel[2];
    __shared__ float ssgn[2];
    __shared__ int   sOff[NN + 1];
    __shared__ int   sCnt[NN];
    __shared__ int   sEid[ET];

    // ---------------- edges (with self loops) + adjacency ----------------
    for (int t = tid; t < ET; t += NTHR) {
        int s, d;
        if (t < E2) { s = gedge[t]; d = gedge[E2 + t]; }
        else        { s = t - E2;   d = t - E2; }
        sSrc[t] = s; sDst[t] = d;
    }
    for (int t = tid; t < NN * NN; t += NTHR) sM[t] = 0.0f;
    for (int i = tid; i < NN; i += NTHR) sCnt[i] = 0;
    __syncthreads();
    for (int t = tid; t < E2; t += NTHR)
        atomicAdd(&sM[sSrc[t] * NN + sDst[t]], 1.0f);
    for (int e = tid; e < ET; e += NTHR)
        atomicAdd(&sCnt[sDst[e]], 1);
    __syncthreads();

    // CSR by dst (deterministic: counts are order-independent, scatter is a
    // serial per-node scan in ascending edge order)
    if (tid == 0) {
        int acc = 0;
        for (int i = 0; i < NN; ++i) { sOff[i] = acc; acc += sCnt[i]; }
        sOff[NN] = acc;
    }
    __syncthreads();
    if (tid < NN) {
        int pos = sOff[tid];
        for (int e = 0; e < ET; ++e)
            if (sDst[e] == tid) sEid[pos++] = e;
    }

    // ---------------- sym-normalized Laplacian ----------------
    for (int i = tid; i < NN; i += NTHR) {
        float dsum = 0.0f;
        for (int j = 0; j < NN; ++j) dsum += sM[i * NN + j];
        sdis[i] = (dsum > 0.0f) ? (1.0f / sqrtf(fmaxf(dsum, 1e-12f))) : 0.0f;
    }
    __syncthreads();
    for (int t = tid; t < NN * NN; t += NTHR) {
        int i = t / NN, j = t % NN;
        sM[t] = ((i == j) ? 1.0f : 0.0f) - sdis[i] * sM[t] * sdis[j];
    }
    for (int t = tid; t < NN * NN; t += NTHR)
        sV[t] = (t / NN == t % NN) ? 1.0f : 0.0f;
    __syncthreads();

    // ---------------- parallel round-robin Jacobi eigensolver ----------------
    // Worker mapping (round-invariant): 250 workers = 25 pairs x 10 chunks of
    // 5 columns. Rotation params computed redundantly per thread (registers,
    // 3 LDS broadcast reads) - no param stage, no rPair lookups. 2 barriers/round.
    {
        const int  jj  = tid / 10;
        const int  k0  = (tid % 10) * 5;
        const bool act = (tid < 250);
        for (int sweep = 0; sweep < SWEEPS; ++sweep) {
            for (int r = 0; r < NN - 1; ++r) {
                int p = 0, q = 0;
                float c = 1.0f, s = 0.0f;
                if (act) {
                    int pv = jj - 1 + r; if (pv >= NN - 1) pv -= NN - 1;
                    p = (jj == 0) ? 0 : pv + 1;
                    int qv = NN - 2 - jj + r; if (qv >= NN - 1) qv -= NN - 1;
                    q = qv + 1;
                    float app = sM[p * NN + p];
                    float aqq = sM[q * NN + q];
                    float apq = sM[p * NN + q];
                    if (fabsf(apq) > 1e-12f) {
                        float tau = (aqq - app) / (2.0f * apq);
                        float tt = ((tau >= 0.0f) ? 1.0f : -1.0f) /
                                   (fabsf(tau) + sqrtf(1.0f + tau * tau));
                        c = 1.0f / sqrtf(1.0f + tt * tt);
                        s = tt * c;
                    }
                    // row phase: rows p,q of sM -> sS
                    const int bp = p * NN, bq = q * NN;
                    for (int k = k0; k < k0 + 5; ++k) {
                        float vp = sM[bp + k], vq = sM[bq + k];
                        sS[bp + k] = c * vp - s * vq;
                        sS[bq + k] = s * vp + c * vq;
                    }
                }
                __syncthreads();
                if (act) {
                    // col phase: cols p,q of sS -> sM, fused V col update
                    for (int k = k0; k < k0 + 5; ++k) {
                        const int row = k * NN;
                        float vp = sS[row + p], vq = sS[row + q];
                        sM[row + p] = c * vp - s * vq;
                        sM[row + q] = s * vp + c * vq;
                        float wp = sV[row + p], wq2 = sV[row + q];
                        sV[row + p] = c * wp - s * wq2;
                        sV[row + q] = s * wp + c * wq2;
                    }
                }
                __syncthreads();
            }
        }
    }

    // ---------------- pick two smallest eigenvalues, canonicalize signs ----------------
    if (tid == 0) {
        int i0 = -1, i1 = -1;
        float e0 = 1e30f, e1 = 1e30f;
        for (int i = 0; i < NN; ++i) {
            float d = sM[i * NN + i];
            if (d < e0)      { e1 = e0; i1 = i0; e0 = d; i0 = i; }
            else if (d < e1) { e1 = d; i1 = i; }
        }
        ssel[0] = i0; ssel[1] = i1;
        for (int cidx = 0; cidx < 2; ++cidx) {
            int col = ssel[cidx];
            float best = -1.0f, bv = 0.0f;
            for (int i = 0; i < NN; ++i) {
                float v = sV[i * NN + col];
                if (fabsf(v) > best) { best = fabsf(v); bv = v; }
            }
            ssgn[cidx] = (bv >= 0.0f) ? 1.0f : -1.0f;
        }
        ssgn[0] *= SIGN0; ssgn[1] *= SIGN1;
    }
    __syncthreads();
    for (int i = tid; i < NN; i += NTHR) {
        sX[i * 5 + 0] = gx[i * 3 + 0];
        sX[i * 5 + 1] = gx[i * 3 + 1];
        sX[i * 5 + 2] = gx[i * 3 + 2];
        sX[i * 5 + 3] = ssgn[0] * sV[i * NN + ssel[0]];
        sX[i * 5 + 4] = ssgn[1] * sV[i * NN + ssel[1]];
    }
    __syncthreads();

    // ---------------- GAT layer 1 (5 -> 8) + ReLU ----------------
    float* h8 = sS;          // 50x8
    float* o8 = sS + 1600;   // 50x8
    for (int t = tid; t < NN * 8; t += NTHR) {
        int i = t >> 3, o = t & 7;
        float acc = 0.0f;
        for (int k = 0; k < 5; ++k) acc += sX[i * 5 + k] * w1[o * 5 + k];
        h8[t] = acc;
    }
    __syncthreads();
    for (int i = tid; i < NN; i += NTHR) {
        float a = 0.0f, b = 0.0f;
        for (int o = 0; o < 8; ++o) {
            a += h8[i * 8 + o] * as1[o];
            b += h8[i * 8 + o] * ad1[o];
        }
        sAs[i] = a; sAd[i] = b;
    }
    __syncthreads();
    for (int e = tid; e < ET; e += NTHR) {
        float v = sAs[sSrc[e]] + sAd[sDst[e]];
        sE[e] = (v > 0.0f) ? v : 0.2f * v;
    }
    __syncthreads();
    for (int i = tid; i < NN; i += NTHR) {
        float m = -1e30f;
        for (int o = sOff[i]; o < sOff[i + 1]; ++o) m = fmaxf(m, sE[sEid[o]]);
        float su = 0.0f;
        for (int o = sOff[i]; o < sOff[i + 1]; ++o) su += expf(sE[sEid[o]] - m);
        sNm[i] = m; sNs[i] = su;
    }
    __syncthreads();
    for (int e = tid; e < ET; e += NTHR)
        sAl[e] = expf(sE[e] - sNm[sDst[e]]) / (sNs[sDst[e]] + 1e-16f);
    __syncthreads();
    for (int t = tid; t < NN * 8; t += NTHR) {
        int i = t >> 3, o = t & 7;
        float acc = b1[o];
        for (int c = sOff[i]; c < sOff[i + 1]; ++c) {
            int e = sEid[c];
            acc += sAl[e] * h8[sSrc[e] * 8 + o];
        }
        o8[t] = fmaxf(acc, 0.0f);
    }
    __syncthreads();

    // ---------------- GAT layer 2 (8 -> 5) ----------------
    for (int t = tid; t < NN * 5; t += NTHR) {
        int i = t / 5, o = t % 5;
        float acc = 0.0f;
        for (int k = 0; k < 8; ++k) acc += o8[i * 8 + k] * w2[o * 8 + k];
        sH5a[t] = acc;
    }
    __syncthreads();
    for (int i = tid; i < NN; i += NTHR) {
        float a = 0.0f, b = 0.0f;
        for (int o = 0; o < 5; ++o) {
            a += sH5a[i * 5 + o] * as2[o];
            b += sH5a[i * 5 + o] * ad2[o];
        }
        sAs[i] = a; sAd[i] = b;
    }
    __syncthreads();
    for (int e = tid; e < ET; e += NTHR) {
        float v = sAs[sSrc[e]] + sAd[sDst[e]];
        sE[e] = (v > 0.0f) ? v : 0.2f * v;
    }
    __syncthreads();
    for (int i = tid; i < NN; i += NTHR) {
        float m = -1e30f;
        for (int o = sOff[i]; o < sOff[i + 1]; ++o) m = fmaxf(m, sE[sEid[o]]);
        float su = 0.0f;
        for (int o = sOff[i]; o < sOff[i + 1]; ++o) su += expf(sE[sEid[o]] - m);
        sNm[i] = m; sNs[i] = su;
    }
    __syncthreads();
    for (int e = tid; e < ET; e += NTHR)
        sAl[e] = expf(sE[e] - sNm[sDst[e]]) / (sNs[sDst[e]] + 1e-16f);
    __syncthreads();
    for (int t = tid; t < NN * 5; t += NTHR) {
        int i = t / 5, o = t % 5;
        float acc = b2[o];
        for (int c = sOff[i]; c < sOff[i + 1]; ++c) {
            int e = sEid[c];
            acc += sAl[e] * sH5a[sSrc[e] * 5 + o];
        }
        sH5b[t] = acc;
    }
    __syncthreads();

    // ---------------- MultiheadAttention (1 head, seq=N) ----------------
    for (int t = tid; t < NN * 15; t += NTHR) {
        int i = t / 15, o = t % 15;
        float acc = mib[o];
        for (int k = 0; k < 5; ++k) acc += sH5b[i * 5 + k] * miw[o * 5 + k];
        if (o < 5)       sH5c[i * 5 + o] = acc;        // q
        else if (o < 10) sH5d[i * 5 + (o - 5)] = acc;  // k
        else             sH5a[i * 5 + (o - 10)] = acc; // v
    }
    __syncthreads();
    const float inv_sqrt5 = 0.4472135954999579f;
    for (int t = tid; t < NN * NN; t += NTHR) {
        int i = t / NN, j = t % NN;
        float acc = 0.0f;
        for (int k = 0; k < 5; ++k) acc += sH5c[i * 5 + k] * sH5d[j * 5 + k];
        sM[t] = acc * inv_sqrt5;
    }
    __syncthreads();
    for (int i = tid; i < NN; i += NTHR) {
        float m = -1e30f;
        for (int j = 0; j < NN; ++j) m = fmaxf(m, sM[i * NN + j]);
        float su = 0.0f;
        for (int j = 0; j < NN; ++j) su += expf(sM[i * NN + j] - m);
        float inv = 1.0f / su;
        for (int j = 0; j < NN; ++j)
            sM[i * NN + j] = expf(sM[i * NN + j] - m) * inv;
    }
    __syncthreads();
    for (int t = tid; t < NN * 5; t += NTHR) {
        int i = t / 5, f = t % 5;
        float acc = 0.0f;
        for (int j = 0; j < NN; ++j) acc += sM[i * NN + j] * sH5a[j * 5 + f];
        sH5c[t] = acc;  // attn @ v
    }
    __syncthreads();
    for (int t = tid; t < NN * 5; t += NTHR) {
        int i = t / 5, o = t % 5;
        float acc = mob[o];
        for (int k = 0; k < 5; ++k) acc += sH5c[i * 5 + k] * mow[o * 5 + k];
        sH5d[t] = acc;  // hM
    }
    __syncthreads();

    // ---------------- TransformerConv ----------------
    for (int t = tid; t < NN * 5; t += NTHR) {
        int i = t / 5, o = t % 5;
        float q_ = bq[o], k_ = bk[o], v_ = bv[o];
        for (int k = 0; k < 5; ++k) {
            float h = sH5d[i * 5 + k];
            q_ += h * wq[o * 5 + k];
            k_ += h * wk[o * 5 + k];
            v_ += h * wv[o * 5 + k];
        }
        sH5a[t] = q_; sH5b[t] = k_; sH5c[t] = v_;
    }
    __syncthreads();
    for (int e = tid; e < ET; e += NTHR) {
        float acc = 0.0f;
        int s2 = sSrc[e], d2 = sDst[e];
        for (int k = 0; k < 5; ++k) acc += sH5a[d2 * 5 + k] * sH5b[s2 * 5 + k];
        sE[e] = acc * inv_sqrt5;
    }
    __syncthreads();
    for (int i = tid; i < NN; i += NTHR) {
        float m = -1e30f;
        for (int o = sOff[i]; o < sOff[i + 1]; ++o) m = fmaxf(m, sE[sEid[o]]);
        float su = 0.0f;
        for (int o = sOff[i]; o < sOff[i + 1]; ++o) su += expf(sE[sEid[o]] - m);
        sNm[i] = m; sNs[i] = su;
    }
    __syncthreads();
    for (int e = tid; e < ET; e += NTHR)
        sAl[e] = expf(sE[e] - sNm[sDst[e]]) / (sNs[sDst[e]] + 1e-16f);
    __syncthreads();
    for (int t = tid; t < NN * 5; t += NTHR) {
        int i = t / 5, o = t % 5;
        float acc = bs[o];
        for (int k = 0; k < 5; ++k) acc += sH5d[i * 5 + k] * ws[o * 5 + k];
        for (int c = sOff[i]; c < sOff[i + 1]; ++c) {
            int e = sEid[c];
            acc += sAl[e] * sH5c[sSrc[e] * 5 + o];
        }
        sH5a[t] = acc;  // tc output
    }
    __syncthreads();

    // ---------------- MLP aggregation head ----------------
    for (int t = tid; t < NN * 64; t += NTHR) {
        int i = t >> 6, o = t & 63;
        float acc = mb1[o];
        for (int k = 0; k < 5; ++k) acc += sH5a[i * 5 + k] * mw1[o * 250 + k];
        sS[t] = fmaxf(acc, 0.0f);
    }
    __syncthreads();
    for (int t = tid; t < NN * NN; t += NTHR) {
        int i = t / NN, j = t % NN;
        float acc = mb2[j];
        for (int k = 0; k < 64; ++k) acc += sS[i * 64 + k] * mw2[j * 64 + k];
        sM[t] = acc;                 // unmasked logits (for value)
        out[t] = acc * gmask[j];     // masked logits output
    }
    __syncthreads();

    // ---------------- value (critic) ----------------
    float part = 0.0f;
    for (int t = tid; t < NN * NN; t += NTHR) part += sM[t] * cw[t % NN];
    sred[tid] = part;
    __syncthreads();
    for (int off = NTHR / 2; off > 0; off >>= 1) {
        if (tid < off) sred[tid] += sred[tid + off];
        __syncthreads();
    }
    if (tid == 0) out[2500] = sred[0] * (1.0f / NN) + cb[0];

    // ---------------- x_combined + ei outputs ----------------
    for (int t = tid; t < NN * 5; t += NTHR) out[2501 + t] = sX[t];
    for (int t = tid; t < 2 * ET; t += NTHR) {
        int row = t / ET, c2 = t % ET;
        int val = (c2 < E2) ? gedge[row * E2 + c2] : (c2 - E2);
        out[2751 + t] = (float)val;
    }
}

extern "C" void kernel_launch(void* const* d_in, const int* in_sizes, int n_in,
                              void* d_out, int out_size, void* d_ws, size_t ws_size,
                              hipStream_t stream) {
    (void)in_sizes; (void)n_in; (void)d_ws; (void)ws_size; (void)out_size;
    opn_kernel<<<1, NTHR, 0, stream>>>(
        (const float*)d_in[0], (const int*)d_in[1], (const float*)d_in[2],
        (const float*)d_in[3], (const float*)d_in[4], (const float*)d_in[5], (const float*)d_in[6],
        (const float*)d_in[7], (const float*)d_in[8], (const float*)d_in[9], (const float*)d_in[10],
        (const float*)d_in[11], (const float*)d_in[12], (const float*)d_in[13], (const float*)d_in[14],
        (const float*)d_in[15], (const float*)d_in[16], (const float*)d_in[17], (const float*)d_in[18],
        (const float*)d_in[19], (const float*)d_in[20], (const float*)d_in[21], (const float*)d_in[22],
        (const float*)d_in[23], (const float*)d_in[24], (const float*)d_in[25], (const float*)d_in[26],
        (const float*)d_in[27], (const float*)d_in[28],
        (float*)d_out);
}

// Round 3
// 182.642 us; speedup vs baseline: 18.2952x; 2.6445x over previous
//
#include <hip/hip_runtime.h>
#include <math.h>

#define NN 50
#define E2 400
#define ET 450
#define NTHR 256
#define KL 40            // Lanczos iterations (deflated space is 49-dim)

__global__ __launch_bounds__(NTHR) void opn_kernel(
    const float* __restrict__ gx, const int* __restrict__ gedge,
    const float* __restrict__ gmask,
    const float* __restrict__ w1, const float* __restrict__ as1,
    const float* __restrict__ ad1, const float* __restrict__ b1,
    const float* __restrict__ w2, const float* __restrict__ as2,
    const float* __restrict__ ad2, const float* __restrict__ b2,
    const float* __restrict__ miw, const float* __restrict__ mib,
    const float* __restrict__ mow, const float* __restrict__ mob,
    const float* __restrict__ wq, const float* __restrict__ bq,
    const float* __restrict__ wk, const float* __restrict__ bk,
    const float* __restrict__ wv, const float* __restrict__ bv,
    const float* __restrict__ ws, const float* __restrict__ bs,
    const float* __restrict__ mw1, const float* __restrict__ mb1,
    const float* __restrict__ mw2, const float* __restrict__ mb2,
    const float* __restrict__ cw, const float* __restrict__ cb,
    float* __restrict__ out)
{
    const int tid = threadIdx.x;

    __shared__ float sM[NN * NN];    // A -> L (kept through Lanczos) -> attn -> logits
    __shared__ float sS[3200];       // partials -> GAT1 h8/o8 -> MLP hid64
    __shared__ float sQ[(KL + 2) * NN];  // q_0 = u0, q_1..q_K Lanczos vectors
    __shared__ float sW[NN];         // Lanczos work vector / Fiedler
    __shared__ float sD[KL + 2];     // CGS coefficients
    __shared__ float sAl_[KL + 2];   // T diagonal (alpha)
    __shared__ float sBe_[KL + 2];   // T off-diagonal (beta)
    __shared__ float sY[KL + 2];     // T eigenvector
    __shared__ float sCp[KL + 2];    // Thomas temp
    __shared__ float sDp2[KL + 2];   // Thomas temp
    __shared__ float sTh[2];         // theta, spare
    __shared__ int   sKeff;
    __shared__ float sX[NN * 5];
    __shared__ float sH5a[NN * 5];
    __shared__ float sH5b[NN * 5];
    __shared__ float sH5c[NN * 5];
    __shared__ float sH5d[NN * 5];
    __shared__ int   sSrc[ET];
    __shared__ int   sDst[ET];
    __shared__ float sE[ET];
    __shared__ float sAl[ET];
    __shared__ float sNm[NN];
    __shared__ float sNs[NN];
    __shared__ float sAs[NN];
    __shared__ float sAd[NN];
    __shared__ float sdis[NN];
    __shared__ float sred[NTHR];
    __shared__ int   sOff[NN + 1];
    __shared__ int   sCnt[NN];
    __shared__ int   sEid[ET];

    // ---------------- edges (with self loops) + adjacency ----------------
    for (int t = tid; t < ET; t += NTHR) {
        int s, d;
        if (t < E2) { s = gedge[t]; d = gedge[E2 + t]; }
        else        { s = t - E2;   d = t - E2; }
        sSrc[t] = s; sDst[t] = d;
    }
    for (int t = tid; t < NN * NN; t += NTHR) sM[t] = 0.0f;
    for (int i = tid; i < NN; i += NTHR) sCnt[i] = 0;
    if (tid == 0) sKeff = KL;
    __syncthreads();
    for (int t = tid; t < E2; t += NTHR)
        atomicAdd(&sM[sSrc[t] * NN + sDst[t]], 1.0f);
    for (int e = tid; e < ET; e += NTHR)
        atomicAdd(&sCnt[sDst[e]], 1);
    __syncthreads();

    // CSR by dst
    if (tid == 0) {
        int acc = 0;
        for (int i = 0; i < NN; ++i) { sOff[i] = acc; acc += sCnt[i]; }
        sOff[NN] = acc;
    }
    __syncthreads();
    if (tid < NN) {
        int pos = sOff[tid];
        for (int e = 0; e < ET; ++e)
            if (sDst[e] == tid) sEid[pos++] = e;
    }

    // ---------------- degree, u0 raw, Laplacian ----------------
    for (int i = tid; i < NN; i += NTHR) {
        float dsum = 0.0f;
        for (int j = 0; j < NN; ++j) dsum += sM[i * NN + j];
        sdis[i] = (dsum > 0.0f) ? (1.0f / sqrtf(fmaxf(dsum, 1e-12f))) : 0.0f;
        sQ[i] = sqrtf(dsum);   // u0 raw = sqrt(deg)
    }
    __syncthreads();
    for (int t = tid; t < NN * NN; t += NTHR) {
        int i = t / NN, j = t % NN;
        sM[t] = ((i == j) ? 1.0f : 0.0f) - sdis[i] * sM[t] * sdis[j];
    }
    // normalize u0; build deterministic start q1 orthogonal to u0 (CGS2)
    if (tid < 64) {
        float q0 = (tid < NN) ? sQ[tid] : 0.0f;
        float nn = q0 * q0;
        for (int off = 32; off > 0; off >>= 1) nn += __shfl_xor(nn, off);
        q0 *= rsqrtf(nn);
        unsigned u = (unsigned)tid * 2654435761u + 12345u;
        u ^= u >> 13; u *= 2246822519u; u ^= u >> 11;
        float q1 = (tid < NN) ? ((float)(u & 0xFFFF) * (1.0f / 65536.0f) - 0.5f) : 0.0f;
        for (int pass = 0; pass < 2; ++pass) {
            float d = q0 * q1;
            for (int off = 32; off > 0; off >>= 1) d += __shfl_xor(d, off);
            q1 -= d * q0;
        }
        float n1 = q1 * q1;
        for (int off = 32; off > 0; off >>= 1) n1 += __shfl_xor(n1, off);
        q1 *= rsqrtf(n1);
        if (tid < NN) { sQ[tid] = q0; sQ[NN + tid] = q1; }
    }
    __syncthreads();

    // ---------------- Lanczos on B = 2I - L (deflated by u0) ----------------
    for (int j = 1; j <= KL; ++j) {
        const int qb = j * NN;
        // Phase A: w = 2 q_j - L q_j   (250 partial workers)
        if (tid < 250) {
            int i = tid / 5, c = tid % 5;
            const int base = i * NN + c * 10, q0i = c * 10;
            float s = 0.0f;
            for (int k = 0; k < 10; ++k) s += sM[base + k] * sQ[qb + q0i + k];
            sS[tid] = s;
        }
        __syncthreads();
        if (tid < NN) {
            float w = 2.0f * sQ[qb + tid]
                    - (sS[5 * tid] + sS[5 * tid + 1] + sS[5 * tid + 2]
                       + sS[5 * tid + 3] + sS[5 * tid + 4]);
            sW[tid] = w;
        }
        if (tid == 0) sAl_[j] = 0.0f;
        __syncthreads();
        // CGS2: orthogonalize w against q_0..q_j (two passes)
        const int M = j + 1;
        for (int pass = 0; pass < 2; ++pass) {
            if (tid < 5 * M) {
                int m = tid / 5, c = tid % 5;
                const int mb = m * NN + c * 10, wb = c * 10;
                float s = 0.0f;
                for (int k = 0; k < 10; ++k) s += sQ[mb + k] * sW[wb + k];
                sS[256 + tid] = s;
            }
            __syncthreads();
            if (tid < M)
                sD[tid] = sS[256 + 5 * tid] + sS[256 + 5 * tid + 1] + sS[256 + 5 * tid + 2]
                        + sS[256 + 5 * tid + 3] + sS[256 + 5 * tid + 4];
            __syncthreads();
            if (tid < NN) {
                float w = sW[tid];
                for (int m = 0; m < M; ++m) w -= sD[m] * sQ[m * NN + tid];
                sW[tid] = w;
            }
            if (tid == 0) sAl_[j] += sD[j];   // alpha_j accumulates across passes
            __syncthreads();
        }
        // beta_j and next vector
        if (tid < 64) {
            float v = (tid < NN) ? sW[tid] : 0.0f;
            float nn = v * v;
            for (int off = 32; off > 0; off >>= 1) nn += __shfl_xor(nn, off);
            if (tid == 0) sBe_[j] = sqrtf(nn);
        }
        __syncthreads();
        float beta = sBe_[j];
        if (j < KL) {
            if (beta > 1e-10f) {
                if (tid < NN) sQ[(j + 1) * NN + tid] = sW[tid] * (1.0f / beta);
            } else if (tid == 0) sKeff = j;
        }
        __syncthreads();
        if (sKeff <= j) break;
    }

    // ---------------- top Ritz pair of T: bisection + inverse iteration ----------------
    const int keff = sKeff;
    if (tid < 64) {
        // Gershgorin bounds (redundant per lane)
        float lo = 1e30f, hi = -1e30f;
        for (int m = 1; m <= keff; ++m) {
            float r = ((m > 1) ? fabsf(sBe_[m - 1]) : 0.0f)
                    + ((m < keff) ? fabsf(sBe_[m]) : 0.0f);
            lo = fminf(lo, sAl_[m] - r);
            hi = fmaxf(hi, sAl_[m] + r);
        }
        for (int round = 0; round < 4; ++round) {
            float h = (hi - lo) * (1.0f / 65.0f);
            float x = lo + (float)(tid + 1) * h;
            int cnt = 0;
            float d = sAl_[1] - x;
            if (d < 0.0f) cnt++;
            for (int m = 2; m <= keff; ++m) {
                float b = sBe_[m - 1];
                float dd = (fabsf(d) < 1e-20f) ? ((d >= 0.0f) ? 1e-20f : -1e-20f) : d;
                d = sAl_[m] - x - b * b / dd;
                if (d < 0.0f) cnt++;
            }
            unsigned long long msk = __ballot(cnt >= keff);
            int f = (msk == 0ULL) ? 64 : (__ffsll((unsigned long long)msk) - 1);
            float nlo = (f == 0) ? lo : (lo + (float)f * h);
            float nhi = (f == 64) ? hi : (lo + (float)(f + 1) * h);
            lo = nlo; hi = nhi;
        }
        if (tid == 0) sTh[0] = 0.5f * (lo + hi);
    }
    __syncthreads();
    if (tid == 0) {
        const float th = sTh[0];
        if (keff == 1) {
            sY[1] = 1.0f;
        } else {
            float inv0 = rsqrtf((float)keff);
            for (int m = 1; m <= keff; ++m) sY[m] = inv0;
            for (int it = 0; it < 2; ++it) {
                float d1 = sAl_[1] - th;
                if (fabsf(d1) < 1e-10f) d1 = (d1 >= 0.0f) ? 1e-10f : -1e-10f;
                sCp[1] = sBe_[1] / d1;
                sDp2[1] = sY[1] / d1;
                for (int m = 2; m <= keff; ++m) {
                    float den = sAl_[m] - th - sBe_[m - 1] * sCp[m - 1];
                    if (fabsf(den) < 1e-10f) den = (den >= 0.0f) ? 1e-10f : -1e-10f;
                    if (m < keff) sCp[m] = sBe_[m] / den;
                    sDp2[m] = (sY[m] - sBe_[m - 1] * sDp2[m - 1]) / den;
                }
                sY[keff] = sDp2[keff];
                for (int m = keff - 1; m >= 1; --m)
                    sY[m] = sDp2[m] - sCp[m] * sY[m + 1];
                float nn = 0.0f;
                for (int m = 1; m <= keff; ++m) nn += sY[m] * sY[m];
                float sc = rsqrtf(nn);
                for (int m = 1; m <= keff; ++m) sY[m] *= sc;
            }
        }
    }
    __syncthreads();
    // Fiedler = Q(1..keff) y, normalize, canonical sign (max-|entry| positive)
    if (tid < NN) {
        float acc = 0.0f;
        for (int m = 1; m <= keff; ++m) acc += sY[m] * sQ[m * NN + tid];
        sW[tid] = acc;
    }
    __syncthreads();
    if (tid < 64) {
        float v = (tid < NN) ? sW[tid] : 0.0f;
        float nn = v * v;
        for (int off = 32; off > 0; off >>= 1) nn += __shfl_xor(nn, off);
        float av = fabsf(v);
        for (int off = 32; off > 0; off >>= 1) av = fmaxf(av, __shfl_xor(av, off));
        unsigned long long msk = __ballot((fabsf(v) == av) && (tid < NN));
        int fl = __ffsll((unsigned long long)msk) - 1;
        float sv = __shfl(v, fl);
        float scale = ((sv >= 0.0f) ? 1.0f : -1.0f) * rsqrtf(nn);
        if (tid < NN) sW[tid] = v * scale;
    }
    __syncthreads();
    for (int i = tid; i < NN; i += NTHR) {
        sX[i * 5 + 0] = gx[i * 3 + 0];
        sX[i * 5 + 1] = gx[i * 3 + 1];
        sX[i * 5 + 2] = gx[i * 3 + 2];
        sX[i * 5 + 3] = sQ[i];    // u0 (all-positive, unit norm)
        sX[i * 5 + 4] = sW[i];    // Fiedler
    }
    __syncthreads();

    // ---------------- GAT layer 1 (5 -> 8) + ReLU ----------------
    float* h8 = sS;          // 50x8
    float* o8 = sS + 1600;   // 50x8
    for (int t = tid; t < NN * 8; t += NTHR) {
        int i = t >> 3, o = t & 7;
        float acc = 0.0f;
        for (int k = 0; k < 5; ++k) acc += sX[i * 5 + k] * w1[o * 5 + k];
        h8[t] = acc;
    }
    __syncthreads();
    for (int i = tid; i < NN; i += NTHR) {
        float a = 0.0f, b = 0.0f;
        for (int o = 0; o < 8; ++o) {
            a += h8[i * 8 + o] * as1[o];
            b += h8[i * 8 + o] * ad1[o];
        }
        sAs[i] = a; sAd[i] = b;
    }
    __syncthreads();
    for (int e = tid; e < ET; e += NTHR) {
        float v = sAs[sSrc[e]] + sAd[sDst[e]];
        sE[e] = (v > 0.0f) ? v : 0.2f * v;
    }
    __syncthreads();
    for (int i = tid; i < NN; i += NTHR) {
        float m = -1e30f;
        for (int o = sOff[i]; o < sOff[i + 1]; ++o) m = fmaxf(m, sE[sEid[o]]);
        float su = 0.0f;
        for (int o = sOff[i]; o < sOff[i + 1]; ++o) su += expf(sE[sEid[o]] - m);
        sNm[i] = m; sNs[i] = su;
    }
    __syncthreads();
    for (int e = tid; e < ET; e += NTHR)
        sAl[e] = expf(sE[e] - sNm[sDst[e]]) / (sNs[sDst[e]] + 1e-16f);
    __syncthreads();
    for (int t = tid; t < NN * 8; t += NTHR) {
        int i = t >> 3, o = t & 7;
        float acc = b1[o];
        for (int c = sOff[i]; c < sOff[i + 1]; ++c) {
            int e = sEid[c];
            acc += sAl[e] * h8[sSrc[e] * 8 + o];
        }
        o8[t] = fmaxf(acc, 0.0f);
    }
    __syncthreads();

    // ---------------- GAT layer 2 (8 -> 5) ----------------
    for (int t = tid; t < NN * 5; t += NTHR) {
        int i = t / 5, o = t % 5;
        float acc = 0.0f;
        for (int k = 0; k < 8; ++k) acc += o8[i * 8 + k] * w2[o * 8 + k];
        sH5a[t] = acc;
    }
    __syncthreads();
    for (int i = tid; i < NN; i += NTHR) {
        float a = 0.0f, b = 0.0f;
        for (int o = 0; o < 5; ++o) {
            a += sH5a[i * 5 + o] * as2[o];
            b += sH5a[i * 5 + o] * ad2[o];
        }
        sAs[i] = a; sAd[i] = b;
    }
    __syncthreads();
    for (int e = tid; e < ET; e += NTHR) {
        float v = sAs[sSrc[e]] + sAd[sDst[e]];
        sE[e] = (v > 0.0f) ? v : 0.2f * v;
    }
    __syncthreads();
    for (int i = tid; i < NN; i += NTHR) {
        float m = -1e30f;
        for (int o = sOff[i]; o < sOff[i + 1]; ++o) m = fmaxf(m, sE[sEid[o]]);
        float su = 0.0f;
        for (int o = sOff[i]; o < sOff[i + 1]; ++o) su += expf(sE[sEid[o]] - m);
        sNm[i] = m; sNs[i] = su;
    }
    __syncthreads();
    for (int e = tid; e < ET; e += NTHR)
        sAl[e] = expf(sE[e] - sNm[sDst[e]]) / (sNs[sDst[e]] + 1e-16f);
    __syncthreads();
    for (int t = tid; t < NN * 5; t += NTHR) {
        int i = t / 5, o = t % 5;
        float acc = b2[o];
        for (int c = sOff[i]; c < sOff[i + 1]; ++c) {
            int e = sEid[c];
            acc += sAl[e] * sH5a[sSrc[e] * 5 + o];
        }
        sH5b[t] = acc;
    }
    __syncthreads();

    // ---------------- MultiheadAttention (1 head, seq=N) ----------------
    for (int t = tid; t < NN * 15; t += NTHR) {
        int i = t / 15, o = t % 15;
        float acc = mib[o];
        for (int k = 0; k < 5; ++k) acc += sH5b[i * 5 + k] * miw[o * 5 + k];
        if (o < 5)       sH5c[i * 5 + o] = acc;        // q
        else if (o < 10) sH5d[i * 5 + (o - 5)] = acc;  // k
        else             sH5a[i * 5 + (o - 10)] = acc; // v
    }
    __syncthreads();
    const float inv_sqrt5 = 0.4472135954999579f;
    for (int t = tid; t < NN * NN; t += NTHR) {
        int i = t / NN, j = t % NN;
        float acc = 0.0f;
        for (int k = 0; k < 5; ++k) acc += sH5c[i * 5 + k] * sH5d[j * 5 + k];
        sM[t] = acc * inv_sqrt5;
    }
    __syncthreads();
    for (int i = tid; i < NN; i += NTHR) {
        float m = -1e30f;
        for (int j = 0; j < NN; ++j) m = fmaxf(m, sM[i * NN + j]);
        float su = 0.0f;
        for (int j = 0; j < NN; ++j) su += expf(sM[i * NN + j] - m);
        float inv = 1.0f / su;
        for (int j = 0; j < NN; ++j)
            sM[i * NN + j] = expf(sM[i * NN + j] - m) * inv;
    }
    __syncthreads();
    for (int t = tid; t < NN * 5; t += NTHR) {
        int i = t / 5, f = t % 5;
        float acc = 0.0f;
        for (int j = 0; j < NN; ++j) acc += sM[i * NN + j] * sH5a[j * 5 + f];
        sH5c[t] = acc;  // attn @ v
    }
    __syncthreads();
    for (int t = tid; t < NN * 5; t += NTHR) {
        int i = t / 5, o = t % 5;
        float acc = mob[o];
        for (int k = 0; k < 5; ++k) acc += sH5c[i * 5 + k] * mow[o * 5 + k];
        sH5d[t] = acc;  // hM
    }
    __syncthreads();

    // ---------------- TransformerConv ----------------
    for (int t = tid; t < NN * 5; t += NTHR) {
        int i = t / 5, o = t % 5;
        float q_ = bq[o], k_ = bk[o], v_ = bv[o];
        for (int k = 0; k < 5; ++k) {
            float h = sH5d[i * 5 + k];
            q_ += h * wq[o * 5 + k];
            k_ += h * wk[o * 5 + k];
            v_ += h * wv[o * 5 + k];
        }
        sH5a[t] = q_; sH5b[t] = k_; sH5c[t] = v_;
    }
    __syncthreads();
    for (int e = tid; e < ET; e += NTHR) {
        float acc = 0.0f;
        int s2 = sSrc[e], d2 = sDst[e];
        for (int k = 0; k < 5; ++k) acc += sH5a[d2 * 5 + k] * sH5b[s2 * 5 + k];
        sE[e] = acc * inv_sqrt5;
    }
    __syncthreads();
    for (int i = tid; i < NN; i += NTHR) {
        float m = -1e30f;
        for (int o = sOff[i]; o < sOff[i + 1]; ++o) m = fmaxf(m, sE[sEid[o]]);
        float su = 0.0f;
        for (int o = sOff[i]; o < sOff[i + 1]; ++o) su += expf(sE[sEid[o]] - m);
        sNm[i] = m; sNs[i] = su;
    }
    __syncthreads();
    for (int e = tid; e < ET; e += NTHR)
        sAl[e] = expf(sE[e] - sNm[sDst[e]]) / (sNs[sDst[e]] + 1e-16f);
    __syncthreads();
    for (int t = tid; t < NN * 5; t += NTHR) {
        int i = t / 5, o = t % 5;
        float acc = bs[o];
        for (int k = 0; k < 5; ++k) acc += sH5d[i * 5 + k] * ws[o * 5 + k];
        for (int c = sOff[i]; c < sOff[i + 1]; ++c) {
            int e = sEid[c];
            acc += sAl[e] * sH5c[sSrc[e] * 5 + o];
        }
        sH5a[t] = acc;  // tc output
    }
    __syncthreads();

    // ---------------- MLP aggregation head ----------------
    for (int t = tid; t < NN * 64; t += NTHR) {
        int i = t >> 6, o = t & 63;
        float acc = mb1[o];
        for (int k = 0; k < 5; ++k) acc += sH5a[i * 5 + k] * mw1[o * 250 + k];
        sS[t] = fmaxf(acc, 0.0f);
    }
    __syncthreads();
    for (int t = tid; t < NN * NN; t += NTHR) {
        int i = t / NN, j = t % NN;
        float acc = mb2[j];
        for (int k = 0; k < 64; ++k) acc += sS[i * 64 + k] * mw2[j * 64 + k];
        sM[t] = acc;                 // unmasked logits (for value)
        out[t] = acc * gmask[j];     // masked logits output
    }
    __syncthreads();

    // ---------------- value (critic) ----------------
    float part = 0.0f;
    for (int t = tid; t < NN * NN; t += NTHR) part += sM[t] * cw[t % NN];
    sred[tid] = part;
    __syncthreads();
    for (int off = NTHR / 2; off > 0; off >>= 1) {
        if (tid < off) sred[tid] += sred[tid + off];
        __syncthreads();
    }
    if (tid == 0) out[2500] = sred[0] * (1.0f / NN) + cb[0];

    // ---------------- x_combined + ei outputs ----------------
    for (int t = tid; t < NN * 5; t += NTHR) out[2501 + t] = sX[t];
    for (int t = tid; t < 2 * ET; t += NTHR) {
        int row = t / ET, c2 = t % ET;
        int val = (c2 < E2) ? gedge[row * E2 + c2] : (c2 - E2);
        out[2751 + t] = (float)val;
    }
}

extern "C" void kernel_launch(void* const* d_in, const int* in_sizes, int n_in,
                              void* d_out, int out_size, void* d_ws, size_t ws_size,
                              hipStream_t stream) {
    (void)in_sizes; (void)n_in; (void)d_ws; (void)ws_size; (void)out_size;
    opn_kernel<<<1, NTHR, 0, stream>>>(
        (const float*)d_in[0], (const int*)d_in[1], (const float*)d_in[2],
        (const float*)d_in[3], (const float*)d_in[4], (const float*)d_in[5], (const float*)d_in[6],
        (const float*)d_in[7], (const float*)d_in[8], (const float*)d_in[9], (const float*)d_in[10],
        (const float*)d_in[11], (const float*)d_in[12], (const float*)d_in[13], (const float*)d_in[14],
        (const float*)d_in[15], (const float*)d_in[16], (const float*)d_in[17], (const float*)d_in[18],
        (const float*)d_in[19], (const float*)d_in[20], (const float*)d_in[21], (const float*)d_in[22],
        (const float*)d_in[23], (const float*)d_in[24], (const float*)d_in[25], (const float*)d_in[26],
        (const float*)d_in[27], (const float*)d_in[28],
        (float*)d_out);
}

// Round 4
// 168.914 us; speedup vs baseline: 19.7820x; 1.0813x over previous
//
#include <hip/hip_runtime.h>
#include <math.h>

#define NN 50
#define E2 400
#define ET 450
#define NTHR 256
#define KL 32            // Lanczos iterations (deflated space is 49-dim)

// Intra-wave LDS handoff fence: drain LDS ops, forbid compiler reordering.
#define WSYNC() do { asm volatile("s_waitcnt lgkmcnt(0)" ::: "memory"); \
                     __builtin_amdgcn_sched_barrier(0); } while (0)

__global__ __launch_bounds__(NTHR) void opn_kernel(
    const float* __restrict__ gx, const int* __restrict__ gedge,
    const float* __restrict__ gmask,
    const float* __restrict__ w1, const float* __restrict__ as1,
    const float* __restrict__ ad1, const float* __restrict__ b1,
    const float* __restrict__ w2, const float* __restrict__ as2,
    const float* __restrict__ ad2, const float* __restrict__ b2,
    const float* __restrict__ miw, const float* __restrict__ mib,
    const float* __restrict__ mow, const float* __restrict__ mob,
    const float* __restrict__ wq, const float* __restrict__ bq,
    const float* __restrict__ wk, const float* __restrict__ bk,
    const float* __restrict__ wv, const float* __restrict__ bv,
    const float* __restrict__ ws, const float* __restrict__ bs,
    const float* __restrict__ mw1, const float* __restrict__ mb1,
    const float* __restrict__ mw2, const float* __restrict__ mb2,
    const float* __restrict__ cw, const float* __restrict__ cb,
    float* __restrict__ out)
{
    const int tid = threadIdx.x;

    __shared__ float sM[NN * NN];    // A -> L (kept through Lanczos) -> attn -> logits
    __shared__ float sS[3200];       // GAT1 h8/o8 -> MLP hid64
    __shared__ float sQ[(KL + 2) * NN];  // q_0 = u0, q_1..q_K Lanczos vectors
    __shared__ float sW[NN];         // Lanczos work vector / Fiedler
    __shared__ float sD[KL + 2];     // CGS coefficients
    __shared__ float sAl_[KL + 2];   // T diagonal (alpha)
    __shared__ float sBe_[KL + 2];   // T off-diagonal (beta)
    __shared__ float sY[KL + 2];     // T eigenvector
    __shared__ float sCp[KL + 2];    // Thomas temp
    __shared__ float sDp2[KL + 2];   // Thomas temp
    __shared__ float sTh[2];         // theta
    __shared__ int   sKeff;
    __shared__ float sX[NN * 5];
    __shared__ float sH5a[NN * 5];
    __shared__ float sH5b[NN * 5];
    __shared__ float sH5c[NN * 5];
    __shared__ float sH5d[NN * 5];
    __shared__ int   sSrc[ET];
    __shared__ int   sDst[ET];
    __shared__ float sE[ET];
    __shared__ float sAl[ET];
    __shared__ float sNm[NN];
    __shared__ float sNs[NN];
    __shared__ float sAs[NN];
    __shared__ float sAd[NN];
    __shared__ float sdis[NN];
    __shared__ float sred[NTHR];
    __shared__ int   sOff[NN + 1];
    __shared__ int   sCnt[NN];
    __shared__ int   sEid[ET];

    // ---------------- edges (with self loops) + adjacency ----------------
    for (int t = tid; t < ET; t += NTHR) {
        int s, d;
        if (t < E2) { s = gedge[t]; d = gedge[E2 + t]; }
        else        { s = t - E2;   d = t - E2; }
        sSrc[t] = s; sDst[t] = d;
    }
    for (int t = tid; t < NN * NN; t += NTHR) sM[t] = 0.0f;
    for (int i = tid; i < NN; i += NTHR) sCnt[i] = 0;
    if (tid == 0) sKeff = KL;
    __syncthreads();
    for (int t = tid; t < E2; t += NTHR)
        atomicAdd(&sM[sSrc[t] * NN + sDst[t]], 1.0f);
    for (int e = tid; e < ET; e += NTHR)
        atomicAdd(&sCnt[sDst[e]], 1);
    __syncthreads();

    // CSR by dst
    if (tid == 0) {
        int acc = 0;
        for (int i = 0; i < NN; ++i) { sOff[i] = acc; acc += sCnt[i]; }
        sOff[NN] = acc;
    }
    __syncthreads();
    if (tid < NN) {
        int pos = sOff[tid];
        for (int e = 0; e < ET; ++e)
            if (sDst[e] == tid) sEid[pos++] = e;
    }

    // ---------------- degree, u0 raw, Laplacian ----------------
    for (int i = tid; i < NN; i += NTHR) {
        float dsum = 0.0f;
        for (int j = 0; j < NN; ++j) dsum += sM[i * NN + j];
        sdis[i] = (dsum > 0.0f) ? (1.0f / sqrtf(fmaxf(dsum, 1e-12f))) : 0.0f;
        sQ[i] = sqrtf(dsum);   // u0 raw = sqrt(deg)
    }
    __syncthreads();
    for (int t = tid; t < NN * NN; t += NTHR) {
        int i = t / NN, j = t % NN;
        sM[t] = ((i == j) ? 1.0f : 0.0f) - sdis[i] * sM[t] * sdis[j];
    }
    // normalize u0; deterministic start q1 orthogonal to u0 (CGS2)
    if (tid < 64) {
        float q0 = (tid < NN) ? sQ[tid] : 0.0f;
        float nn = q0 * q0;
        for (int off = 32; off > 0; off >>= 1) nn += __shfl_xor(nn, off);
        q0 *= rsqrtf(nn);
        unsigned u = (unsigned)tid * 2654435761u + 12345u;
        u ^= u >> 13; u *= 2246822519u; u ^= u >> 11;
        float q1 = (tid < NN) ? ((float)(u & 0xFFFF) * (1.0f / 65536.0f) - 0.5f) : 0.0f;
        for (int pass = 0; pass < 2; ++pass) {
            float d = q0 * q1;
            for (int off = 32; off > 0; off >>= 1) d += __shfl_xor(d, off);
            q1 -= d * q0;
        }
        float n1 = q1 * q1;
        for (int off = 32; off > 0; off >>= 1) n1 += __shfl_xor(n1, off);
        q1 *= rsqrtf(n1);
        if (tid < NN) { sQ[tid] = q0; sQ[NN + tid] = q1; }
    }
    __syncthreads();

    // ---------------- Lanczos on B = 2I - L: SINGLE WAVE, zero barriers ----------------
    if (tid < 64) {
        const int lane = tid;
        for (int j = 1; j <= KL; ++j) {
            const int qb = j * NN;
            // w_i = 2 q_i - (L q)_i   (lane i owns row i)
            float w = 0.0f;
            if (lane < NN) {
                float acc = 0.0f;
                const int rb = lane * NN;
                for (int k = 0; k < NN; ++k) acc += sM[rb + k] * sQ[qb + k];
                w = 2.0f * sQ[qb + lane] - acc;
            }
            float alpha = 0.0f;
            // CGS2: two full reorthogonalization passes against q_0..q_j
            for (int pass = 0; pass < 2; ++pass) {
                if (lane < NN) sW[lane] = w;
                WSYNC();
                if (lane <= j) {                 // lane m computes c_m = q_m . w
                    float c = 0.0f;
                    const int mb = lane * NN;
                    for (int i = 0; i < NN; ++i) c += sQ[mb + i] * sW[i];
                    sD[lane] = c;
                }
                WSYNC();
                alpha += sD[j];
                if (lane < NN) {
                    float acc2 = 0.0f;
                    for (int m = 0; m <= j; ++m) acc2 += sD[m] * sQ[m * NN + lane];
                    w -= acc2;
                }
                WSYNC();                          // sD reads done before next pass writes
            }
            // beta = ||w||, store T entries, emit next vector
            float nn = w * w;
            for (int off = 32; off > 0; off >>= 1) nn += __shfl_xor(nn, off);
            float beta = sqrtf(nn);
            if (lane == 0) { sAl_[j] = alpha; sBe_[j] = beta; }
            if (j < KL) {
                if (beta > 1e-10f) {
                    if (lane < NN) sQ[(j + 1) * NN + lane] = w * (1.0f / beta);
                    WSYNC();
                } else {
                    if (lane == 0) sKeff = j;
                    break;                        // beta uniform across lanes
                }
            }
        }
    }
    __syncthreads();

    // ---------------- top Ritz pair of T: bisection + inverse iteration ----------------
    const int keff = sKeff;
    if (tid < 64) {
        float lo = 1e30f, hi = -1e30f;
        for (int m = 1; m <= keff; ++m) {
            float r = ((m > 1) ? fabsf(sBe_[m - 1]) : 0.0f)
                    + ((m < keff) ? fabsf(sBe_[m]) : 0.0f);
            lo = fminf(lo, sAl_[m] - r);
            hi = fmaxf(hi, sAl_[m] + r);
        }
        for (int round = 0; round < 4; ++round) {
            float h = (hi - lo) * (1.0f / 65.0f);
            float x = lo + (float)(tid + 1) * h;
            int cnt = 0;
            float d = sAl_[1] - x;
            if (d < 0.0f) cnt++;
            for (int m = 2; m <= keff; ++m) {
                float b = sBe_[m - 1];
                float dd = (fabsf(d) < 1e-20f) ? ((d >= 0.0f) ? 1e-20f : -1e-20f) : d;
                d = sAl_[m] - x - b * b / dd;
                if (d < 0.0f) cnt++;
            }
            unsigned long long msk = __ballot(cnt >= keff);
            int f = (msk == 0ULL) ? 64 : (__ffsll((unsigned long long)msk) - 1);
            float nlo = (f == 0) ? lo : (lo + (float)f * h);
            float nhi = (f == 64) ? hi : (lo + (float)(f + 1) * h);
            lo = nlo; hi = nhi;
        }
        if (tid == 0) sTh[0] = 0.5f * (lo + hi);
    }
    __syncthreads();
    if (tid == 0) {
        const float th = sTh[0];
        if (keff == 1) {
            sY[1] = 1.0f;
        } else {
            float inv0 = rsqrtf((float)keff);
            for (int m = 1; m <= keff; ++m) sY[m] = inv0;
            for (int it = 0; it < 2; ++it) {
                float d1 = sAl_[1] - th;
                if (fabsf(d1) < 1e-10f) d1 = (d1 >= 0.0f) ? 1e-10f : -1e-10f;
                sCp[1] = sBe_[1] / d1;
                sDp2[1] = sY[1] / d1;
                for (int m = 2; m <= keff; ++m) {
                    float den = sAl_[m] - th - sBe_[m - 1] * sCp[m - 1];
                    if (fabsf(den) < 1e-10f) den = (den >= 0.0f) ? 1e-10f : -1e-10f;
                    if (m < keff) sCp[m] = sBe_[m] / den;
                    sDp2[m] = (sY[m] - sBe_[m - 1] * sDp2[m - 1]) / den;
                }
                sY[keff] = sDp2[keff];
                for (int m = keff - 1; m >= 1; --m)
                    sY[m] = sDp2[m] - sCp[m] * sY[m + 1];
                float nn = 0.0f;
                for (int m = 1; m <= keff; ++m) nn += sY[m] * sY[m];
                float sc = rsqrtf(nn);
                for (int m = 1; m <= keff; ++m) sY[m] *= sc;
            }
        }
    }
    __syncthreads();
    // Fiedler = Q(1..keff) y, normalize, canonical sign (max-|entry| positive)
    if (tid < NN) {
        float acc = 0.0f;
        for (int m = 1; m <= keff; ++m) acc += sY[m] * sQ[m * NN + tid];
        sW[tid] = acc;
    }
    __syncthreads();
    if (tid < 64) {
        float v = (tid < NN) ? sW[tid] : 0.0f;
        float nn = v * v;
        for (int off = 32; off > 0; off >>= 1) nn += __shfl_xor(nn, off);
        float av = fabsf(v);
        for (int off = 32; off > 0; off >>= 1) av = fmaxf(av, __shfl_xor(av, off));
        unsigned long long msk = __ballot((fabsf(v) == av) && (tid < NN));
        int fl = __ffsll((unsigned long long)msk) - 1;
        float sv = __shfl(v, fl);
        float scale = ((sv >= 0.0f) ? 1.0f : -1.0f) * rsqrtf(nn);
        if (tid < NN) sW[tid] = v * scale;
    }
    __syncthreads();
    for (int i = tid; i < NN; i += NTHR) {
        sX[i * 5 + 0] = gx[i * 3 + 0];
        sX[i * 5 + 1] = gx[i * 3 + 1];
        sX[i * 5 + 2] = gx[i * 3 + 2];
        sX[i * 5 + 3] = sQ[i];    // u0 (all-positive, unit norm)
        sX[i * 5 + 4] = sW[i];    // Fiedler
    }
    __syncthreads();

    // ---------------- GAT layer 1 (5 -> 8) + ReLU ----------------
    float* h8 = sS;          // 50x8
    float* o8 = sS + 1600;   // 50x8
    for (int t = tid; t < NN * 8; t += NTHR) {
        int i = t >> 3, o = t & 7;
        float acc = 0.0f;
        for (int k = 0; k < 5; ++k) acc += sX[i * 5 + k] * w1[o * 5 + k];
        h8[t] = acc;
    }
    __syncthreads();
    for (int i = tid; i < NN; i += NTHR) {
        float a = 0.0f, b = 0.0f;
        for (int o = 0; o < 8; ++o) {
            a += h8[i * 8 + o] * as1[o];
            b += h8[i * 8 + o] * ad1[o];
        }
        sAs[i] = a; sAd[i] = b;
    }
    __syncthreads();
    for (int e = tid; e < ET; e += NTHR) {
        float v = sAs[sSrc[e]] + sAd[sDst[e]];
        sE[e] = (v > 0.0f) ? v : 0.2f * v;
    }
    __syncthreads();
    for (int i = tid; i < NN; i += NTHR) {
        float m = -1e30f;
        for (int o = sOff[i]; o < sOff[i + 1]; ++o) m = fmaxf(m, sE[sEid[o]]);
        float su = 0.0f;
        for (int o = sOff[i]; o < sOff[i + 1]; ++o) su += expf(sE[sEid[o]] - m);
        sNm[i] = m; sNs[i] = su;
    }
    __syncthreads();
    for (int e = tid; e < ET; e += NTHR)
        sAl[e] = expf(sE[e] - sNm[sDst[e]]) / (sNs[sDst[e]] + 1e-16f);
    __syncthreads();
    for (int t = tid; t < NN * 8; t += NTHR) {
        int i = t >> 3, o = t & 7;
        float acc = b1[o];
        for (int c = sOff[i]; c < sOff[i + 1]; ++c) {
            int e = sEid[c];
            acc += sAl[e] * h8[sSrc[e] * 8 + o];
        }
        o8[t] = fmaxf(acc, 0.0f);
    }
    __syncthreads();

    // ---------------- GAT layer 2 (8 -> 5) ----------------
    for (int t = tid; t < NN * 5; t += NTHR) {
        int i = t / 5, o = t % 5;
        float acc = 0.0f;
        for (int k = 0; k < 8; ++k) acc += o8[i * 8 + k] * w2[o * 8 + k];
        sH5a[t] = acc;
    }
    __syncthreads();
    for (int i = tid; i < NN; i += NTHR) {
        float a = 0.0f, b = 0.0f;
        for (int o = 0; o < 5; ++o) {
            a += sH5a[i * 5 + o] * as2[o];
            b += sH5a[i * 5 + o] * ad2[o];
        }
        sAs[i] = a; sAd[i] = b;
    }
    __syncthreads();
    for (int e = tid; e < ET; e += NTHR) {
        float v = sAs[sSrc[e]] + sAd[sDst[e]];
        sE[e] = (v > 0.0f) ? v : 0.2f * v;
    }
    __syncthreads();
    for (int i = tid; i < NN; i += NTHR) {
        float m = -1e30f;
        for (int o = sOff[i]; o < sOff[i + 1]; ++o) m = fmaxf(m, sE[sEid[o]]);
        float su = 0.0f;
        for (int o = sOff[i]; o < sOff[i + 1]; ++o) su += expf(sE[sEid[o]] - m);
        sNm[i] = m; sNs[i] = su;
    }
    __syncthreads();
    for (int e = tid; e < ET; e += NTHR)
        sAl[e] = expf(sE[e] - sNm[sDst[e]]) / (sNs[sDst[e]] + 1e-16f);
    __syncthreads();
    for (int t = tid; t < NN * 5; t += NTHR) {
        int i = t / 5, o = t % 5;
        float acc = b2[o];
        for (int c = sOff[i]; c < sOff[i + 1]; ++c) {
            int e = sEid[c];
            acc += sAl[e] * sH5a[sSrc[e] * 5 + o];
        }
        sH5b[t] = acc;
    }
    __syncthreads();

    // ---------------- MultiheadAttention (1 head, seq=N) ----------------
    for (int t = tid; t < NN * 15; t += NTHR) {
        int i = t / 15, o = t % 15;
        float acc = mib[o];
        for (int k = 0; k < 5; ++k) acc += sH5b[i * 5 + k] * miw[o * 5 + k];
        if (o < 5)       sH5c[i * 5 + o] = acc;        // q
        else if (o < 10) sH5d[i * 5 + (o - 5)] = acc;  // k
        else             sH5a[i * 5 + (o - 10)] = acc; // v
    }
    __syncthreads();
    const float inv_sqrt5 = 0.4472135954999579f;
    for (int t = tid; t < NN * NN; t += NTHR) {
        int i = t / NN, j = t % NN;
        float acc = 0.0f;
        for (int k = 0; k < 5; ++k) acc += sH5c[i * 5 + k] * sH5d[j * 5 + k];
        sM[t] = acc * inv_sqrt5;
    }
    __syncthreads();
    for (int i = tid; i < NN; i += NTHR) {
        float m = -1e30f;
        for (int j = 0; j < NN; ++j) m = fmaxf(m, sM[i * NN + j]);
        float su = 0.0f;
        for (int j = 0; j < NN; ++j) su += expf(sM[i * NN + j] - m);
        float inv = 1.0f / su;
        for (int j = 0; j < NN; ++j)
            sM[i * NN + j] = expf(sM[i * NN + j] - m) * inv;
    }
    __syncthreads();
    for (int t = tid; t < NN * 5; t += NTHR) {
        int i = t / 5, f = t % 5;
        float acc = 0.0f;
        for (int j = 0; j < NN; ++j) acc += sM[i * NN + j] * sH5a[j * 5 + f];
        sH5c[t] = acc;  // attn @ v
    }
    __syncthreads();
    for (int t = tid; t < NN * 5; t += NTHR) {
        int i = t / 5, o = t % 5;
        float acc = mob[o];
        for (int k = 0; k < 5; ++k) acc += sH5c[i * 5 + k] * mow[o * 5 + k];
        sH5d[t] = acc;  // hM
    }
    __syncthreads();

    // ---------------- TransformerConv ----------------
    for (int t = tid; t < NN * 5; t += NTHR) {
        int i = t / 5, o = t % 5;
        float q_ = bq[o], k_ = bk[o], v_ = bv[o];
        for (int k = 0; k < 5; ++k) {
            float h = sH5d[i * 5 + k];
            q_ += h * wq[o * 5 + k];
            k_ += h * wk[o * 5 + k];
            v_ += h * wv[o * 5 + k];
        }
        sH5a[t] = q_; sH5b[t] = k_; sH5c[t] = v_;
    }
    __syncthreads();
    for (int e = tid; e < ET; e += NTHR) {
        float acc = 0.0f;
        int s2 = sSrc[e], d2 = sDst[e];
        for (int k = 0; k < 5; ++k) acc += sH5a[d2 * 5 + k] * sH5b[s2 * 5 + k];
        sE[e] = acc * inv_sqrt5;
    }
    __syncthreads();
    for (int i = tid; i < NN; i += NTHR) {
        float m = -1e30f;
        for (int o = sOff[i]; o < sOff[i + 1]; ++o) m = fmaxf(m, sE[sEid[o]]);
        float su = 0.0f;
        for (int o = sOff[i]; o < sOff[i + 1]; ++o) su += expf(sE[sEid[o]] - m);
        sNm[i] = m; sNs[i] = su;
    }
    __syncthreads();
    for (int e = tid; e < ET; e += NTHR)
        sAl[e] = expf(sE[e] - sNm[sDst[e]]) / (sNs[sDst[e]] + 1e-16f);
    __syncthreads();
    for (int t = tid; t < NN * 5; t += NTHR) {
        int i = t / 5, o = t % 5;
        float acc = bs[o];
        for (int k = 0; k < 5; ++k) acc += sH5d[i * 5 + k] * ws[o * 5 + k];
        for (int c = sOff[i]; c < sOff[i + 1]; ++c) {
            int e = sEid[c];
            acc += sAl[e] * sH5c[sSrc[e] * 5 + o];
        }
        sH5a[t] = acc;  // tc output
    }
    __syncthreads();

    // ---------------- MLP aggregation head ----------------
    for (int t = tid; t < NN * 64; t += NTHR) {
        int i = t >> 6, o = t & 63;
        float acc = mb1[o];
        for (int k = 0; k < 5; ++k) acc += sH5a[i * 5 + k] * mw1[o * 250 + k];
        sS[t] = fmaxf(acc, 0.0f);
    }
    __syncthreads();
    for (int t = tid; t < NN * NN; t += NTHR) {
        int i = t / NN, j = t % NN;
        float acc = mb2[j];
        for (int k = 0; k < 64; ++k) acc += sS[i * 64 + k] * mw2[j * 64 + k];
        sM[t] = acc;                 // unmasked logits (for value)
        out[t] = acc * gmask[j];     // masked logits output
    }
    __syncthreads();

    // ---------------- value (critic) ----------------
    float part = 0.0f;
    for (int t = tid; t < NN * NN; t += NTHR) part += sM[t] * cw[t % NN];
    sred[tid] = part;
    __syncthreads();
    for (int off = NTHR / 2; off > 0; off >>= 1) {
        if (tid < off) sred[tid] += sred[tid + off];
        __syncthreads();
    }
    if (tid == 0) out[2500] = sred[0] * (1.0f / NN) + cb[0];

    // ---------------- x_combined + ei outputs ----------------
    for (int t = tid; t < NN * 5; t += NTHR) out[2501 + t] = sX[t];
    for (int t = tid; t < 2 * ET; t += NTHR) {
        int row = t / ET, c2 = t % ET;
        int val = (c2 < E2) ? gedge[row * E2 + c2] : (c2 - E2);
        out[2751 + t] = (float)val;
    }
}

extern "C" void kernel_launch(void* const* d_in, const int* in_sizes, int n_in,
                              void* d_out, int out_size, void* d_ws, size_t ws_size,
                              hipStream_t stream) {
    (void)in_sizes; (void)n_in; (void)d_ws; (void)ws_size; (void)out_size;
    opn_kernel<<<1, NTHR, 0, stream>>>(
        (const float*)d_in[0], (const int*)d_in[1], (const float*)d_in[2],
        (const float*)d_in[3], (const float*)d_in[4], (const float*)d_in[5], (const float*)d_in[6],
        (const float*)d_in[7], (const float*)d_in[8], (const float*)d_in[9], (const float*)d_in[10],
        (const float*)d_in[11], (const float*)d_in[12], (const float*)d_in[13], (const float*)d_in[14],
        (const float*)d_in[15], (const float*)d_in[16], (const float*)d_in[17], (const float*)d_in[18],
        (const float*)d_in[19], (const float*)d_in[20], (const float*)d_in[21], (const float*)d_in[22],
        (const float*)d_in[23], (const float*)d_in[24], (const float*)d_in[25], (const float*)d_in[26],
        (const float*)d_in[27], (const float*)d_in[28],
        (float*)d_out);
}